// Round 25
// baseline (109.602 us; speedup 1.0000x reference)
//
#include <hip/hip_runtime.h>
#include <stdint.h>

#define DIM 1024
#define MOE_HID 512
#define SH_HID 2048
#define NE 16
#define NT 2048
#define ROWS_CAP 6144   // 4096 assignments + 16*127 max padding

typedef unsigned short u16;
typedef __attribute__((ext_vector_type(8))) short s16x8;
typedef __attribute__((ext_vector_type(4))) float f32x4;

// one barrier per K-step: own ds ops retired -> barrier -> (loads ahead) -> ds_reads -> MFMA
#define SYNC_BAR() \
  asm volatile("s_waitcnt lgkmcnt(0)" ::: "memory"); \
  __builtin_amdgcn_sched_barrier(0); \
  __builtin_amdgcn_s_barrier(); \
  __builtin_amdgcn_sched_barrier(0);

__device__ __forceinline__ u16 f2bf(float f){
  union { float f; unsigned v; } x; x.f = f;
  unsigned r = x.v + 0x7FFF + ((x.v >> 16) & 1);
  return (u16)(r >> 16);
}

// packed f32->bf16 (RNE), 2 elems/op
__device__ __forceinline__ s16x8 cvt8pk(float4 a, float4 b){
  union { s16x8 v; unsigned u[4]; } r;
  asm volatile("v_cvt_pk_bf16_f32 %0, %1, %2" : "=v"(r.u[0]) : "v"(a.x), "v"(a.y));
  asm volatile("v_cvt_pk_bf16_f32 %0, %1, %2" : "=v"(r.u[1]) : "v"(a.z), "v"(a.w));
  asm volatile("v_cvt_pk_bf16_f32 %0, %1, %2" : "=v"(r.u[2]) : "v"(b.x), "v"(b.y));
  asm volatile("v_cvt_pk_bf16_f32 %0, %1, %2" : "=v"(r.u[3]) : "v"(b.z), "v"(b.w));
  return r.v;
}

// ---------------- router (+ fused fp32->bf16 conversion of x) ----------------
__global__ void k_router(const float* __restrict__ x, const float* __restrict__ Wg,
                         const float* __restrict__ Wsgate1,
                         int* __restrict__ inds, float* __restrict__ scores,
                         float* __restrict__ gl, u16* __restrict__ xb){
  int lane = threadIdx.x & 63;
  int t = blockIdx.x * 4 + (threadIdx.x >> 6);
  const float4* xt = (const float4*)(x + (size_t)t * DIM);
  float4 xv[4];
#pragma unroll
  for(int j = 0; j < 4; j++) xv[j] = xt[lane + 64 * j];

  // write bf16 copy of x (fused cvt)
#pragma unroll
  for(int j = 0; j < 4; j++){
    ushort4 o;
    o.x = f2bf(xv[j].x); o.y = f2bf(xv[j].y); o.z = f2bf(xv[j].z); o.w = f2bf(xv[j].w);
    *(ushort4*)(xb + (size_t)t * DIM + 4 * (lane + 64 * j)) = o;
  }

  float acc[NE + 1];
#pragma unroll
  for(int e = 0; e <= NE; e++) acc[e] = 0.f;

#pragma unroll
  for(int e = 0; e < NE; e++){
    const float4* wr = (const float4*)(Wg + (size_t)e * DIM);
#pragma unroll
    for(int j = 0; j < 4; j++){
      float4 w = wr[lane + 64 * j];
      acc[e] += xv[j].x * w.x + xv[j].y * w.y + xv[j].z * w.z + xv[j].w * w.w;
    }
  }
  {
    const float4* wr = (const float4*)Wsgate1;
#pragma unroll
    for(int j = 0; j < 4; j++){
      float4 w = wr[lane + 64 * j];
      acc[NE] += xv[j].x * w.x + xv[j].y * w.y + xv[j].z * w.z + xv[j].w * w.w;
    }
  }

#pragma unroll
  for(int off = 32; off; off >>= 1)
#pragma unroll
    for(int e = 0; e <= NE; e++) acc[e] += __shfl_xor(acc[e], off, 64);

  if(lane == 0){
    int b0 = 0; float v0 = acc[0];
    for(int e = 1; e < NE; e++) if(acc[e] > v0){ v0 = acc[e]; b0 = e; }
    int b1 = (b0 == 0) ? 1 : 0; float v1 = acc[b1];
    for(int e = 0; e < NE; e++) if(e != b0 && acc[e] > v1){ v1 = acc[e]; b1 = e; }
    float s0 = 1.f / (1.f + __expf(v1 - v0));
    inds[t*2+0] = b0; inds[t*2+1] = b1;
    scores[t*2+0] = s0; scores[t*2+1] = 1.f - s0;
    gl[t] = acc[NE];
  }
}

// ---------------- assign: histogram + prefix (128-padded) + rows ----------------
__global__ void k_assign(const int* __restrict__ inds, const float* __restrict__ scores,
                         int* __restrict__ counts, int* __restrict__ offs,
                         int* __restrict__ rowinfo, float* __restrict__ rowscore){
  __shared__ int cnt[NE], off_s[NE], fill[NE];
  int tid = threadIdx.x;
  if(tid < NE){ cnt[tid] = 0; fill[tid] = 0; }
  __syncthreads();
  int ea[4];
#pragma unroll
  for(int i = 0; i < 4; i++){
    int a = tid + 1024 * i;
    ea[i] = inds[a];
    atomicAdd(&cnt[ea[i]], 1);
  }
  __syncthreads();
  if(tid == 0){
    int o = 0;
    for(int e = 0; e < NE; e++){
      off_s[e] = o;
      o += (cnt[e] + 127) & ~127;
    }
  }
  __syncthreads();
#pragma unroll
  for(int i = 0; i < 4; i++){
    int a = tid + 1024 * i;
    int e = ea[i];
    int row = off_s[e] + atomicAdd(&fill[e], 1);
    rowinfo[row] = a;
    rowscore[row] = scores[a];
  }
  if(tid < NE){ counts[tid] = cnt[tid]; offs[tid] = off_s[tid]; }
}

// ================= FUSED gate+up: 896 blocks, BK=32, 32KB LDS, XCD-aware swizzle =============
// logical = (bid%8)*112 + bid/8  (bijective; 896 = 8*112). Each XCD gets a contiguous
// 112-logical-block chunk -> weight-panel reuse lands in that XCD's L2.
// logical<384: expert (row-major: same-expert tiles contiguous).
// logical>=384: shared, PANEL-major (16 same-panel row-tiles contiguous).
__global__ __launch_bounds__(256, 2) void k_gateup_fused(
    const u16* __restrict__ xb, const int* __restrict__ rowinfo,
    const float* __restrict__ Weg, const float* __restrict__ Weu,
    const float* __restrict__ Wsg, const float* __restrict__ Wsu,
    u16* __restrict__ Hm, u16* __restrict__ Hs,
    const int* __restrict__ counts, const int* __restrict__ offs){
  __shared__ __align__(16) u16 As[2][128 * 32];
  __shared__ __align__(16) u16 Bgs[2][64 * 32];
  __shared__ __align__(16) u16 Bus[2][64 * 32];

  const int logical = (blockIdx.x & 7) * 112 + (blockIdx.x >> 3);
  const int tid = threadIdx.x, lane = tid & 63, wid = tid >> 6;
  const int wm = wid >> 1, wn = wid & 1;
  const int srow = tid >> 2, p8 = (tid & 3) * 8;
  const int swz8 = (((tid & 3) ^ ((tid >> 3) & 3))) * 8;
  const int fr = lane & 15;
  const int fkswz = (((lane >> 4) ^ ((lane >> 1) & 3))) * 8;
  const int wA0 = srow * 32 + swz8, wA1 = (64 + srow) * 32 + swz8;
  const int wB = srow * 32 + swz8;

  const u16 *Ar0, *Ar1;
  const float *Bgr, *Bur;
  u16* H; int ldh;

  if(logical < 384){
    // ---------------- expert path (row-major logical order) ----------------
    const int row0 = (logical >> 3) * 128;
    const int n0 = (logical & 7) * 64;
    const int rows_used = offs[NE-1] + ((counts[NE-1] + 127) & ~127);
    if(row0 >= rows_used) return;
    int e = 0;
#pragma unroll
    for(int k = 1; k < NE; k++) if(row0 >= offs[k]) e = k;

    int a0 = rowinfo[row0 + srow];
    int a1 = rowinfo[row0 + 64 + srow];
    int t0 = ((unsigned)a0 < 4096u) ? (a0 >> 1) : 0;
    int t1 = ((unsigned)a1 < 4096u) ? (a1 >> 1) : 0;
    Ar0 = xb + (size_t)t0 * DIM + p8;
    Ar1 = xb + (size_t)t1 * DIM + p8;
    Bgr = Weg + (size_t)e * MOE_HID * DIM + (size_t)(n0 + srow) * DIM + p8;
    Bur = Weu + (size_t)e * MOE_HID * DIM + (size_t)(n0 + srow) * DIM + p8;
    H = Hm + (size_t)row0 * MOE_HID + n0;
    ldh = MOE_HID;
  } else {
    // ---------------- shared path (panel-major logical order) ----------------
    const int s = logical - 384;
    const int n0 = (s >> 4) * 64;       // panel index: 16 consecutive logical ids share it
    const int row0 = (s & 15) * 128;
    Ar0 = xb + (size_t)(row0 + srow) * DIM + p8;
    Ar1 = xb + (size_t)(row0 + 64 + srow) * DIM + p8;
    Bgr = Wsg + (size_t)(n0 + srow) * DIM + p8;
    Bur = Wsu + (size_t)(n0 + srow) * DIM + p8;
    H = Hs + (size_t)row0 * SH_HID + n0;
    ldh = SH_HID;
  }

  uint4 aE0, aE1, aO0, aO1;
  float4 gE0, gE1, uE0, uE1, gO0, gO1, uO0, uO1;

#define GF_LOAD(S, ko) \
  a##S##0 = *(const uint4*)(Ar0 + (ko));  a##S##1 = *(const uint4*)(Ar1 + (ko)); \
  g##S##0 = *(const float4*)(Bgr + (ko)); g##S##1 = *(const float4*)(Bgr + (ko) + 4); \
  u##S##0 = *(const float4*)(Bur + (ko)); u##S##1 = *(const float4*)(Bur + (ko) + 4);

  f32x4 accg[4][2], accu[4][2];
#pragma unroll
  for(int m = 0; m < 4; m++)
#pragma unroll
    for(int n = 0; n < 2; n++){
      accg[m][n] = (f32x4){0.f,0.f,0.f,0.f};
      accu[m][n] = (f32x4){0.f,0.f,0.f,0.f};
    }

  GF_LOAD(E, 0)
  GF_LOAD(O, 32)

#define GF_STEP(tt, S, bb) { \
  *(uint4*)(As[bb] + wA0) = a##S##0; \
  *(uint4*)(As[bb] + wA1) = a##S##1; \
  *(s16x8*)(Bgs[bb] + wB) = cvt8pk(g##S##0, g##S##1); \
  *(s16x8*)(Bus[bb] + wB) = cvt8pk(u##S##0, u##S##1); \
  SYNC_BAR() \
  if((tt) + 2 < 32){ GF_LOAD(S, ((tt) + 2) * 32) } \
  s16x8 af[4], bgf[2], buf2[2]; \
  _Pragma("unroll") for(int m = 0; m < 4; m++) \
    af[m] = *(const s16x8*)(As[bb] + (wm*64 + m*16 + fr) * 32 + fkswz); \
  _Pragma("unroll") for(int n = 0; n < 2; n++){ \
    bgf[n]  = *(const s16x8*)(Bgs[bb] + (wn*32 + n*16 + fr) * 32 + fkswz); \
    buf2[n] = *(const s16x8*)(Bus[bb] + (wn*32 + n*16 + fr) * 32 + fkswz); } \
  _Pragma("unroll") for(int m = 0; m < 4; m++) \
  _Pragma("unroll") for(int n = 0; n < 2; n++){ \
    accg[m][n] = __builtin_amdgcn_mfma_f32_16x16x32_bf16(af[m], bgf[n], accg[m][n], 0, 0, 0); \
    accu[m][n] = __builtin_amdgcn_mfma_f32_16x16x32_bf16(af[m], buf2[n], accu[m][n], 0, 0, 0); } }

  for(int t = 0; t < 32; t += 2){
    GF_STEP(t,     E, 0)
    GF_STEP(t + 1, O, 1)
  }

#pragma unroll
  for(int m = 0; m < 4; m++)
#pragma unroll
    for(int n = 0; n < 2; n++)
#pragma unroll
      for(int i = 0; i < 4; i++){
        int r = wm*64 + m*16 + ((lane >> 4) << 2) + i;
        int c = wn*32 + n*16 + (lane & 15);
        float g = accg[m][n][i], u = accu[m][n][i];
        float h = (g / (1.f + __expf(-g))) * u;
        H[(size_t)r * ldh + c] = f2bf(h);
      }
}

// ================= down GEMM: DENSE grid (8 n, 80 y): y<32 shared (mtile,kz), y>=32 expert =====
// (R16/R18/R21-proven body; plain stores to yp/Sh0/Sh1)
__global__ __launch_bounds__(256, 2) void k_down_all(
    const u16* __restrict__ Hm, const u16* __restrict__ Hs,
    const float* __restrict__ Wed, const float* __restrict__ Wsd,
    float* __restrict__ yp, float* __restrict__ Sh0, float* __restrict__ Sh1,
    const int* __restrict__ counts, const int* __restrict__ offs,
    const int* __restrict__ rowinfo, const float* __restrict__ rowscore){
  __shared__ __align__(16) u16 As[2][128 * 32];
  __shared__ __align__(16) u16 Bs[2][128 * 32];

  const int y = blockIdx.y, n0 = blockIdx.x * 128;
  const bool sh = (y < 32);
  const u16* A; const float* B; float* O = yp;
  int lda, M = NT, row0 = 0, kBeg = 0, nk, lrow = 0;
  if(sh){
    int mtile = y & 15, kz = y >> 4;
    A = Hs + (size_t)mtile * 128 * SH_HID; lda = SH_HID;
    B = Wsd; kBeg = kz * 1024; nk = 32;
    O = (kz == 0) ? Sh0 : Sh1;
    row0 = mtile * 128;
  } else {
    row0 = (y - 32) * 128;
    int rows_used = offs[NE-1] + ((counts[NE-1] + 127) & ~127);
    if(row0 >= rows_used) return;
    int e = 0;
#pragma unroll
    for(int k = 1; k < NE; k++) if(row0 >= offs[k]) e = k;
    M = counts[e];
    lrow = row0 - offs[e];
    A = Hm + (size_t)row0 * MOE_HID; lda = MOE_HID;
    B = Wed + (size_t)e * DIM * MOE_HID; nk = 16;
  }

  const int tid = threadIdx.x, lane = tid & 63, wid = tid >> 6;
  const int wm = wid >> 1, wn = wid & 1;
  const int srow = tid >> 2, p8 = (tid & 3) * 8;
  const int swz8 = (((tid & 3) ^ ((tid >> 3) & 3))) * 8;
  const int fr = lane & 15;
  const int fkswz = (((lane >> 4) ^ ((lane >> 1) & 3))) * 8;
  const int wA0 = srow * 32 + swz8, wA1 = (64 + srow) * 32 + swz8;

  const u16* Ar0 = A + (size_t)srow * lda + kBeg + p8;
  const u16* Ar1 = A + (size_t)(64 + srow) * lda + kBeg + p8;
  const float* Br0 = B + (size_t)(n0 + srow) * lda + kBeg + p8;
  const float* Br1 = B + (size_t)(n0 + 64 + srow) * lda + kBeg + p8;

  uint4 aE0, aE1, aO0, aO1;
  float4 bE00, bE01, bE10, bE11, bO00, bO01, bO10, bO11;

#define DN_LOAD(S, ko) \
  a##S##0 = *(const uint4*)(Ar0 + (ko));   a##S##1 = *(const uint4*)(Ar1 + (ko)); \
  b##S##00 = *(const float4*)(Br0 + (ko)); b##S##01 = *(const float4*)(Br0 + (ko) + 4); \
  b##S##10 = *(const float4*)(Br1 + (ko)); b##S##11 = *(const float4*)(Br1 + (ko) + 4);

  f32x4 acc[4][4];
#pragma unroll
  for(int m = 0; m < 4; m++)
#pragma unroll
    for(int n = 0; n < 4; n++) acc[m][n] = (f32x4){0.f,0.f,0.f,0.f};

  DN_LOAD(E, 0)
  DN_LOAD(O, 32)

#define DN_STEP(tt, S, bb) { \
  *(uint4*)(As[bb] + wA0) = a##S##0; \
  *(uint4*)(As[bb] + wA1) = a##S##1; \
  *(s16x8*)(Bs[bb] + wA0) = cvt8pk(b##S##00, b##S##01); \
  *(s16x8*)(Bs[bb] + wA1) = cvt8pk(b##S##10, b##S##11); \
  SYNC_BAR() \
  if((tt) + 2 < nk){ DN_LOAD(S, ((tt) + 2) * 32) } \
  s16x8 af[4], bf[4]; \
  _Pragma("unroll") for(int m = 0; m < 4; m++) \
    af[m] = *(const s16x8*)(As[bb] + (wm*64 + m*16 + fr) * 32 + fkswz); \
  _Pragma("unroll") for(int n = 0; n < 4; n++) \
    bf[n] = *(const s16x8*)(Bs[bb] + (wn*64 + n*16 + fr) * 32 + fkswz); \
  _Pragma("unroll") for(int m = 0; m < 4; m++) \
  _Pragma("unroll") for(int n = 0; n < 4; n++) \
    acc[m][n] = __builtin_amdgcn_mfma_f32_16x16x32_bf16(af[m], bf[n], acc[m][n], 0, 0, 0); }

  for(int t = 0; t < nk; t += 2){
    DN_STEP(t,     E, 0)
    DN_STEP(t + 1, O, 1)
  }

#pragma unroll
  for(int m = 0; m < 4; m++)
#pragma unroll
    for(int i = 0; i < 4; i++){
      int rl = wm*64 + m*16 + ((lane >> 4) << 2) + i;
      if(sh){
        float* orow = O + (size_t)(row0 + rl) * DIM + n0 + wn*64 + (lane & 15);
#pragma unroll
        for(int n = 0; n < 4; n++) orow[n*16] = acc[m][n][i];
      } else if(lrow + rl < M){
        int ar = row0 + rl;
        int slot = rowinfo[ar];
        float sc = rowscore[ar];
        float* orow = yp + (size_t)slot * DIM + n0 + wn*64 + (lane & 15);
#pragma unroll
        for(int n = 0; n < 4; n++) orow[n*16] = sc * acc[m][n][i];
      }
    }
}

// ---------------- combine ----------------
__global__ void k_combine(const float* __restrict__ yp, const float* __restrict__ Sh0,
                          const float* __restrict__ Sh1,
                          const float* __restrict__ gl, float* __restrict__ out){
  int idx = (blockIdx.x * 256 + threadIdx.x) * 4;
  int t = idx >> 10;
  float s = 1.f / (1.f + __expf(-gl[t]));
  float4 a = *(const float4*)(yp + (size_t)(t*2)   * DIM + (idx & 1023));
  float4 b = *(const float4*)(yp + (size_t)(t*2+1) * DIM + (idx & 1023));
  float4 c0 = *(const float4*)(Sh0 + idx);
  float4 c1 = *(const float4*)(Sh1 + idx);
  float4 o;
  o.x = a.x + b.x + s * (c0.x + c1.x);
  o.y = a.y + b.y + s * (c0.y + c1.y);
  o.z = a.z + b.z + s * (c0.z + c1.z);
  o.w = a.w + b.w + s * (c0.w + c1.w);
  *(float4*)(out + idx) = o;
}

extern "C" void kernel_launch(void* const* d_in, const int* in_sizes, int n_in,
                              void* d_out, int out_size, void* d_ws, size_t ws_size,
                              hipStream_t stream){
  const float* x    = (const float*)d_in[0];
  const float* Wg   = (const float*)d_in[1];
  const float* Weg  = (const float*)d_in[2];
  const float* Weu  = (const float*)d_in[3];
  const float* Wed  = (const float*)d_in[4];
  const float* Wsg  = (const float*)d_in[5];
  const float* Wsu  = (const float*)d_in[6];
  const float* Wsd  = (const float*)d_in[7];
  const float* Wg1  = (const float*)d_in[8];
  float* out = (float*)d_out;

  // small control arrays first, big tensors after
  char* p = (char*)d_ws;
  int* inds   = (int*)p;  p += 4096 * 4;
  float* scores = (float*)p; p += 4096 * 4;
  float* gl   = (float*)p;  p += NT * 4;
  int* counts = (int*)p;  p += 64;
  int* offs   = (int*)p;  p += 64;
  int* rowinfo = (int*)p; p += ROWS_CAP * 4;
  float* rowscore = (float*)p; p += ROWS_CAP * 4;
  u16* xb     = (u16*)p;  p += (size_t)NT * DIM * 2;
  u16* Hs     = (u16*)p;  p += (size_t)NT * SH_HID * 2;
  float* Sh0  = (float*)p; p += (size_t)NT * DIM * 4;
  float* Sh1  = (float*)p; p += (size_t)NT * DIM * 4;
  u16* Hm     = (u16*)p;  p += (size_t)ROWS_CAP * MOE_HID * 2;
  float* yp   = (float*)p; p += (size_t)NT * 2 * DIM * 4;

  k_router<<<NT/4, 256, 0, stream>>>(x, Wg, Wg1, inds, scores, gl, xb);
  k_assign<<<1, 1024, 0, stream>>>(inds, scores, counts, offs, rowinfo, rowscore);

  // fused gate+up: BK=32, 32KB LDS, XCD-aware swizzled grid (panel reuse -> per-XCD L2)
  k_gateup_fused<<<896, 256, 0, stream>>>(xb, rowinfo, Weg, Weu, Wsg, Wsu,
                                          Hm, Hs, counts, offs);
  // down: dense grid 8 n x (32 shared + 48 expert tiles)
  k_down_all<<<dim3(8, 80), 256, 0, stream>>>(Hm, Hs, Wed, Wsd,
                                              yp, Sh0, Sh1, counts, offs,
                                              rowinfo, rowscore);

  k_combine<<<2048, 256, 0, stream>>>(yp, Sh0, Sh1, gl, out);
}

// Round 26
// 104.999 us; speedup vs baseline: 1.0438x; 1.0438x over previous
//
#include <hip/hip_runtime.h>
#include <stdint.h>

#define DIM 1024
#define MOE_HID 512
#define SH_HID 2048
#define NE 16
#define NT 2048
#define ROWS_CAP 6144   // 4096 assignments + 16*127 max padding

typedef unsigned short u16;
typedef __attribute__((ext_vector_type(8))) short s16x8;
typedef __attribute__((ext_vector_type(4))) float f32x4;

// one barrier per K-step: own ds ops retired -> barrier -> (loads ahead) -> ds_reads -> MFMA
#define SYNC_BAR() \
  asm volatile("s_waitcnt lgkmcnt(0)" ::: "memory"); \
  __builtin_amdgcn_sched_barrier(0); \
  __builtin_amdgcn_s_barrier(); \
  __builtin_amdgcn_sched_barrier(0);

__device__ __forceinline__ u16 f2bf(float f){
  union { float f; unsigned v; } x; x.f = f;
  unsigned r = x.v + 0x7FFF + ((x.v >> 16) & 1);
  return (u16)(r >> 16);
}

// packed f32->bf16 (RNE), 2 elems/op
__device__ __forceinline__ s16x8 cvt8pk(float4 a, float4 b){
  union { s16x8 v; unsigned u[4]; } r;
  asm volatile("v_cvt_pk_bf16_f32 %0, %1, %2" : "=v"(r.u[0]) : "v"(a.x), "v"(a.y));
  asm volatile("v_cvt_pk_bf16_f32 %0, %1, %2" : "=v"(r.u[1]) : "v"(a.z), "v"(a.w));
  asm volatile("v_cvt_pk_bf16_f32 %0, %1, %2" : "=v"(r.u[2]) : "v"(b.x), "v"(b.y));
  asm volatile("v_cvt_pk_bf16_f32 %0, %1, %2" : "=v"(r.u[3]) : "v"(b.z), "v"(b.w));
  return r.v;
}

// ---------------- router (+ fused fp32->bf16 conversion of x) ----------------
__global__ void k_router(const float* __restrict__ x, const float* __restrict__ Wg,
                         const float* __restrict__ Wsgate1,
                         int* __restrict__ inds, float* __restrict__ scores,
                         float* __restrict__ gl, u16* __restrict__ xb){
  int lane = threadIdx.x & 63;
  int t = blockIdx.x * 4 + (threadIdx.x >> 6);
  const float4* xt = (const float4*)(x + (size_t)t * DIM);
  float4 xv[4];
#pragma unroll
  for(int j = 0; j < 4; j++) xv[j] = xt[lane + 64 * j];

  // write bf16 copy of x (fused cvt)
#pragma unroll
  for(int j = 0; j < 4; j++){
    ushort4 o;
    o.x = f2bf(xv[j].x); o.y = f2bf(xv[j].y); o.z = f2bf(xv[j].z); o.w = f2bf(xv[j].w);
    *(ushort4*)(xb + (size_t)t * DIM + 4 * (lane + 64 * j)) = o;
  }

  float acc[NE + 1];
#pragma unroll
  for(int e = 0; e <= NE; e++) acc[e] = 0.f;

#pragma unroll
  for(int e = 0; e < NE; e++){
    const float4* wr = (const float4*)(Wg + (size_t)e * DIM);
#pragma unroll
    for(int j = 0; j < 4; j++){
      float4 w = wr[lane + 64 * j];
      acc[e] += xv[j].x * w.x + xv[j].y * w.y + xv[j].z * w.z + xv[j].w * w.w;
    }
  }
  {
    const float4* wr = (const float4*)Wsgate1;
#pragma unroll
    for(int j = 0; j < 4; j++){
      float4 w = wr[lane + 64 * j];
      acc[NE] += xv[j].x * w.x + xv[j].y * w.y + xv[j].z * w.z + xv[j].w * w.w;
    }
  }

#pragma unroll
  for(int off = 32; off; off >>= 1)
#pragma unroll
    for(int e = 0; e <= NE; e++) acc[e] += __shfl_xor(acc[e], off, 64);

  if(lane == 0){
    int b0 = 0; float v0 = acc[0];
    for(int e = 1; e < NE; e++) if(acc[e] > v0){ v0 = acc[e]; b0 = e; }
    int b1 = (b0 == 0) ? 1 : 0; float v1 = acc[b1];
    for(int e = 0; e < NE; e++) if(e != b0 && acc[e] > v1){ v1 = acc[e]; b1 = e; }
    float s0 = 1.f / (1.f + __expf(v1 - v0));
    inds[t*2+0] = b0; inds[t*2+1] = b1;
    scores[t*2+0] = s0; scores[t*2+1] = 1.f - s0;
    gl[t] = acc[NE];
  }
}

// ---------------- assign: histogram + prefix (128-padded) + rows ----------------
__global__ void k_assign(const int* __restrict__ inds, const float* __restrict__ scores,
                         int* __restrict__ counts, int* __restrict__ offs,
                         int* __restrict__ rowinfo, float* __restrict__ rowscore){
  __shared__ int cnt[NE], off_s[NE], fill[NE];
  int tid = threadIdx.x;
  if(tid < NE){ cnt[tid] = 0; fill[tid] = 0; }
  __syncthreads();
  int ea[4];
#pragma unroll
  for(int i = 0; i < 4; i++){
    int a = tid + 1024 * i;
    ea[i] = inds[a];
    atomicAdd(&cnt[ea[i]], 1);
  }
  __syncthreads();
  if(tid == 0){
    int o = 0;
    for(int e = 0; e < NE; e++){
      off_s[e] = o;
      o += (cnt[e] + 127) & ~127;
    }
  }
  __syncthreads();
#pragma unroll
  for(int i = 0; i < 4; i++){
    int a = tid + 1024 * i;
    int e = ea[i];
    int row = off_s[e] + atomicAdd(&fill[e], 1);
    rowinfo[row] = a;
    rowscore[row] = scores[a];
  }
  if(tid < NE){ counts[tid] = cnt[tid]; offs[tid] = off_s[tid]; }
}

// ================= FUSED gate+up: 896 blocks, BK=32, 32KB LDS, 4-DEEP reg pipeline ===========
// bid<384: expert (gather-A via rowinfo, offs-scan). bid>=384: shared (linear A).
// E/O/P/Q register sets, loads issued 4 K-steps ahead; 2 LDS buffers, 1 barrier/step.
__global__ __launch_bounds__(256, 2) void k_gateup_fused(
    const u16* __restrict__ xb, const int* __restrict__ rowinfo,
    const float* __restrict__ Weg, const float* __restrict__ Weu,
    const float* __restrict__ Wsg, const float* __restrict__ Wsu,
    u16* __restrict__ Hm, u16* __restrict__ Hs,
    const int* __restrict__ counts, const int* __restrict__ offs){
  __shared__ __align__(16) u16 As[2][128 * 32];
  __shared__ __align__(16) u16 Bgs[2][64 * 32];
  __shared__ __align__(16) u16 Bus[2][64 * 32];

  const int bid = blockIdx.x;
  const int tid = threadIdx.x, lane = tid & 63, wid = tid >> 6;
  const int wm = wid >> 1, wn = wid & 1;
  const int srow = tid >> 2, p8 = (tid & 3) * 8;
  const int swz8 = (((tid & 3) ^ ((tid >> 3) & 3))) * 8;
  const int fr = lane & 15;
  const int fkswz = (((lane >> 4) ^ ((lane >> 1) & 3))) * 8;
  const int wA0 = srow * 32 + swz8, wA1 = (64 + srow) * 32 + swz8;
  const int wB = srow * 32 + swz8;

  const u16 *Ar0, *Ar1;
  const float *Bgr, *Bur;
  u16* H; int ldh;

  if(bid < 384){
    // ---------------- expert path ----------------
    const int row0 = (bid >> 3) * 128;
    const int n0 = (bid & 7) * 64;
    const int rows_used = offs[NE-1] + ((counts[NE-1] + 127) & ~127);
    if(row0 >= rows_used) return;
    int e = 0;
#pragma unroll
    for(int k = 1; k < NE; k++) if(row0 >= offs[k]) e = k;

    int a0 = rowinfo[row0 + srow];
    int a1 = rowinfo[row0 + 64 + srow];
    int t0 = ((unsigned)a0 < 4096u) ? (a0 >> 1) : 0;
    int t1 = ((unsigned)a1 < 4096u) ? (a1 >> 1) : 0;
    Ar0 = xb + (size_t)t0 * DIM + p8;
    Ar1 = xb + (size_t)t1 * DIM + p8;
    Bgr = Weg + (size_t)e * MOE_HID * DIM + (size_t)(n0 + srow) * DIM + p8;
    Bur = Weu + (size_t)e * MOE_HID * DIM + (size_t)(n0 + srow) * DIM + p8;
    H = Hm + (size_t)row0 * MOE_HID + n0;
    ldh = MOE_HID;
  } else {
    // ---------------- shared path ----------------
    const int i = bid - 384;
    const int row0 = (i >> 5) * 128;
    const int n0 = (i & 31) * 64;
    Ar0 = xb + (size_t)(row0 + srow) * DIM + p8;
    Ar1 = xb + (size_t)(row0 + 64 + srow) * DIM + p8;
    Bgr = Wsg + (size_t)(n0 + srow) * DIM + p8;
    Bur = Wsu + (size_t)(n0 + srow) * DIM + p8;
    H = Hs + (size_t)row0 * SH_HID + n0;
    ldh = SH_HID;
  }

  uint4 aE0, aE1, aO0, aO1, aP0, aP1, aQ0, aQ1;
  float4 gE0, gE1, uE0, uE1, gO0, gO1, uO0, uO1;
  float4 gP0, gP1, uP0, uP1, gQ0, gQ1, uQ0, uQ1;

#define GF_LOAD(S, ko) \
  a##S##0 = *(const uint4*)(Ar0 + (ko));  a##S##1 = *(const uint4*)(Ar1 + (ko)); \
  g##S##0 = *(const float4*)(Bgr + (ko)); g##S##1 = *(const float4*)(Bgr + (ko) + 4); \
  u##S##0 = *(const float4*)(Bur + (ko)); u##S##1 = *(const float4*)(Bur + (ko) + 4);

  f32x4 accg[4][2], accu[4][2];
#pragma unroll
  for(int m = 0; m < 4; m++)
#pragma unroll
    for(int n = 0; n < 2; n++){
      accg[m][n] = (f32x4){0.f,0.f,0.f,0.f};
      accu[m][n] = (f32x4){0.f,0.f,0.f,0.f};
    }

  GF_LOAD(E, 0)
  GF_LOAD(O, 32)
  GF_LOAD(P, 64)
  GF_LOAD(Q, 96)

#define GF_STEP(tt, S, bb) { \
  *(uint4*)(As[bb] + wA0) = a##S##0; \
  *(uint4*)(As[bb] + wA1) = a##S##1; \
  *(s16x8*)(Bgs[bb] + wB) = cvt8pk(g##S##0, g##S##1); \
  *(s16x8*)(Bus[bb] + wB) = cvt8pk(u##S##0, u##S##1); \
  SYNC_BAR() \
  if((tt) + 4 < 32){ GF_LOAD(S, ((tt) + 4) * 32) } \
  s16x8 af[4], bgf[2], buf2[2]; \
  _Pragma("unroll") for(int m = 0; m < 4; m++) \
    af[m] = *(const s16x8*)(As[bb] + (wm*64 + m*16 + fr) * 32 + fkswz); \
  _Pragma("unroll") for(int n = 0; n < 2; n++){ \
    bgf[n]  = *(const s16x8*)(Bgs[bb] + (wn*32 + n*16 + fr) * 32 + fkswz); \
    buf2[n] = *(const s16x8*)(Bus[bb] + (wn*32 + n*16 + fr) * 32 + fkswz); } \
  _Pragma("unroll") for(int m = 0; m < 4; m++) \
  _Pragma("unroll") for(int n = 0; n < 2; n++){ \
    accg[m][n] = __builtin_amdgcn_mfma_f32_16x16x32_bf16(af[m], bgf[n], accg[m][n], 0, 0, 0); \
    accu[m][n] = __builtin_amdgcn_mfma_f32_16x16x32_bf16(af[m], buf2[n], accu[m][n], 0, 0, 0); } }

  for(int t = 0; t < 32; t += 4){
    GF_STEP(t,     E, 0)
    GF_STEP(t + 1, O, 1)
    GF_STEP(t + 2, P, 0)
    GF_STEP(t + 3, Q, 1)
  }

#pragma unroll
  for(int m = 0; m < 4; m++)
#pragma unroll
    for(int n = 0; n < 2; n++)
#pragma unroll
      for(int i = 0; i < 4; i++){
        int r = wm*64 + m*16 + ((lane >> 4) << 2) + i;
        int c = wn*32 + n*16 + (lane & 15);
        float g = accg[m][n][i], u = accu[m][n][i];
        float h = (g / (1.f + __expf(-g))) * u;
        H[(size_t)r * ldh + c] = f2bf(h);
      }
}

// ================= down GEMM: DENSE grid (8 n, 80 y): y<32 shared (mtile,kz), y>=32 expert =====
// (R16/R18/R21-proven body; plain stores to yp/Sh0/Sh1)
__global__ __launch_bounds__(256, 2) void k_down_all(
    const u16* __restrict__ Hm, const u16* __restrict__ Hs,
    const float* __restrict__ Wed, const float* __restrict__ Wsd,
    float* __restrict__ yp, float* __restrict__ Sh0, float* __restrict__ Sh1,
    const int* __restrict__ counts, const int* __restrict__ offs,
    const int* __restrict__ rowinfo, const float* __restrict__ rowscore){
  __shared__ __align__(16) u16 As[2][128 * 32];
  __shared__ __align__(16) u16 Bs[2][128 * 32];

  const int y = blockIdx.y, n0 = blockIdx.x * 128;
  const bool sh = (y < 32);
  const u16* A; const float* B; float* O = yp;
  int lda, M = NT, row0 = 0, kBeg = 0, nk, lrow = 0;
  if(sh){
    int mtile = y & 15, kz = y >> 4;
    A = Hs + (size_t)mtile * 128 * SH_HID; lda = SH_HID;
    B = Wsd; kBeg = kz * 1024; nk = 32;
    O = (kz == 0) ? Sh0 : Sh1;
    row0 = mtile * 128;
  } else {
    row0 = (y - 32) * 128;
    int rows_used = offs[NE-1] + ((counts[NE-1] + 127) & ~127);
    if(row0 >= rows_used) return;
    int e = 0;
#pragma unroll
    for(int k = 1; k < NE; k++) if(row0 >= offs[k]) e = k;
    M = counts[e];
    lrow = row0 - offs[e];
    A = Hm + (size_t)row0 * MOE_HID; lda = MOE_HID;
    B = Wed + (size_t)e * DIM * MOE_HID; nk = 16;
  }

  const int tid = threadIdx.x, lane = tid & 63, wid = tid >> 6;
  const int wm = wid >> 1, wn = wid & 1;
  const int srow = tid >> 2, p8 = (tid & 3) * 8;
  const int swz8 = (((tid & 3) ^ ((tid >> 3) & 3))) * 8;
  const int fr = lane & 15;
  const int fkswz = (((lane >> 4) ^ ((lane >> 1) & 3))) * 8;
  const int wA0 = srow * 32 + swz8, wA1 = (64 + srow) * 32 + swz8;

  const u16* Ar0 = A + (size_t)srow * lda + kBeg + p8;
  const u16* Ar1 = A + (size_t)(64 + srow) * lda + kBeg + p8;
  const float* Br0 = B + (size_t)(n0 + srow) * lda + kBeg + p8;
  const float* Br1 = B + (size_t)(n0 + 64 + srow) * lda + kBeg + p8;

  uint4 aE0, aE1, aO0, aO1;
  float4 bE00, bE01, bE10, bE11, bO00, bO01, bO10, bO11;

#define DN_LOAD(S, ko) \
  a##S##0 = *(const uint4*)(Ar0 + (ko));   a##S##1 = *(const uint4*)(Ar1 + (ko)); \
  b##S##00 = *(const float4*)(Br0 + (ko)); b##S##01 = *(const float4*)(Br0 + (ko) + 4); \
  b##S##10 = *(const float4*)(Br1 + (ko)); b##S##11 = *(const float4*)(Br1 + (ko) + 4);

  f32x4 acc[4][4];
#pragma unroll
  for(int m = 0; m < 4; m++)
#pragma unroll
    for(int n = 0; n < 4; n++) acc[m][n] = (f32x4){0.f,0.f,0.f,0.f};

  DN_LOAD(E, 0)
  DN_LOAD(O, 32)

#define DN_STEP(tt, S, bb) { \
  *(uint4*)(As[bb] + wA0) = a##S##0; \
  *(uint4*)(As[bb] + wA1) = a##S##1; \
  *(s16x8*)(Bs[bb] + wA0) = cvt8pk(b##S##00, b##S##01); \
  *(s16x8*)(Bs[bb] + wA1) = cvt8pk(b##S##10, b##S##11); \
  SYNC_BAR() \
  if((tt) + 2 < nk){ DN_LOAD(S, ((tt) + 2) * 32) } \
  s16x8 af[4], bf[4]; \
  _Pragma("unroll") for(int m = 0; m < 4; m++) \
    af[m] = *(const s16x8*)(As[bb] + (wm*64 + m*16 + fr) * 32 + fkswz); \
  _Pragma("unroll") for(int n = 0; n < 4; n++) \
    bf[n] = *(const s16x8*)(Bs[bb] + (wn*64 + n*16 + fr) * 32 + fkswz); \
  _Pragma("unroll") for(int m = 0; m < 4; m++) \
  _Pragma("unroll") for(int n = 0; n < 4; n++) \
    acc[m][n] = __builtin_amdgcn_mfma_f32_16x16x32_bf16(af[m], bf[n], acc[m][n], 0, 0, 0); }

  for(int t = 0; t < nk; t += 2){
    DN_STEP(t,     E, 0)
    DN_STEP(t + 1, O, 1)
  }

#pragma unroll
  for(int m = 0; m < 4; m++)
#pragma unroll
    for(int i = 0; i < 4; i++){
      int rl = wm*64 + m*16 + ((lane >> 4) << 2) + i;
      if(sh){
        float* orow = O + (size_t)(row0 + rl) * DIM + n0 + wn*64 + (lane & 15);
#pragma unroll
        for(int n = 0; n < 4; n++) orow[n*16] = acc[m][n][i];
      } else if(lrow + rl < M){
        int ar = row0 + rl;
        int slot = rowinfo[ar];
        float sc = rowscore[ar];
        float* orow = yp + (size_t)slot * DIM + n0 + wn*64 + (lane & 15);
#pragma unroll
        for(int n = 0; n < 4; n++) orow[n*16] = sc * acc[m][n][i];
      }
    }
}

// ---------------- combine ----------------
__global__ void k_combine(const float* __restrict__ yp, const float* __restrict__ Sh0,
                          const float* __restrict__ Sh1,
                          const float* __restrict__ gl, float* __restrict__ out){
  int idx = (blockIdx.x * 256 + threadIdx.x) * 4;
  int t = idx >> 10;
  float s = 1.f / (1.f + __expf(-gl[t]));
  float4 a = *(const float4*)(yp + (size_t)(t*2)   * DIM + (idx & 1023));
  float4 b = *(const float4*)(yp + (size_t)(t*2+1) * DIM + (idx & 1023));
  float4 c0 = *(const float4*)(Sh0 + idx);
  float4 c1 = *(const float4*)(Sh1 + idx);
  float4 o;
  o.x = a.x + b.x + s * (c0.x + c1.x);
  o.y = a.y + b.y + s * (c0.y + c1.y);
  o.z = a.z + b.z + s * (c0.z + c1.z);
  o.w = a.w + b.w + s * (c0.w + c1.w);
  *(float4*)(out + idx) = o;
}

extern "C" void kernel_launch(void* const* d_in, const int* in_sizes, int n_in,
                              void* d_out, int out_size, void* d_ws, size_t ws_size,
                              hipStream_t stream){
  const float* x    = (const float*)d_in[0];
  const float* Wg   = (const float*)d_in[1];
  const float* Weg  = (const float*)d_in[2];
  const float* Weu  = (const float*)d_in[3];
  const float* Wed  = (const float*)d_in[4];
  const float* Wsg  = (const float*)d_in[5];
  const float* Wsu  = (const float*)d_in[6];
  const float* Wsd  = (const float*)d_in[7];
  const float* Wg1  = (const float*)d_in[8];
  float* out = (float*)d_out;

  // small control arrays first, big tensors after
  char* p = (char*)d_ws;
  int* inds   = (int*)p;  p += 4096 * 4;
  float* scores = (float*)p; p += 4096 * 4;
  float* gl   = (float*)p;  p += NT * 4;
  int* counts = (int*)p;  p += 64;
  int* offs   = (int*)p;  p += 64;
  int* rowinfo = (int*)p; p += ROWS_CAP * 4;
  float* rowscore = (float*)p; p += ROWS_CAP * 4;
  u16* xb     = (u16*)p;  p += (size_t)NT * DIM * 2;
  u16* Hs     = (u16*)p;  p += (size_t)NT * SH_HID * 2;
  float* Sh0  = (float*)p; p += (size_t)NT * DIM * 4;
  float* Sh1  = (float*)p; p += (size_t)NT * DIM * 4;
  u16* Hm     = (u16*)p;  p += (size_t)ROWS_CAP * MOE_HID * 2;
  float* yp   = (float*)p; p += (size_t)NT * 2 * DIM * 4;

  k_router<<<NT/4, 256, 0, stream>>>(x, Wg, Wg1, inds, scores, gl, xb);
  k_assign<<<1, 1024, 0, stream>>>(inds, scores, counts, offs, rowinfo, rowscore);

  // fused gate+up: BK=32, 32KB LDS, 4-deep reg pipeline, linear dispatch
  k_gateup_fused<<<896, 256, 0, stream>>>(xb, rowinfo, Weg, Weu, Wsg, Wsu,
                                          Hm, Hs, counts, offs);
  // down: dense grid 8 n x (32 shared + 48 expert tiles)
  k_down_all<<<dim3(8, 80), 256, 0, stream>>>(Hm, Hs, Wed, Wsd,
                                              yp, Sh0, Sh1, counts, offs,
                                              rowinfo, rowscore);

  k_combine<<<2048, 256, 0, stream>>>(yp, Sh0, Sh1, gl, out);
}